// Round 1
// baseline (55.009 us; speedup 1.0000x reference)
//
#include <hip/hip_runtime.h>
#include <stdint.h>

// Problem constants (from reference): x shape [T*B, C, H, W] = [256, 128, 32, 32]
static constexpr int   T_  = 8;
static constexpr int   C_  = 128;
static constexpr int   N_  = 32 * 128 * 32 * 32;  // B*C*H*W = 4194304 sites
static constexpr float LR_ = 0.1f;

// ---------------------------------------------------------------------------
// K1: IF recurrence over T, pack spike bits, per-channel new_thre reduction.
// Each thread owns 4 consecutive sites (float4 loads). A block covers 1024
// consecutive sites = exactly one (b,c) H*W plane, so channel is block-uniform.
// ---------------------------------------------------------------------------
template <bool PACK>
__global__ __launch_bounds__(256) void k_fwd(const float* __restrict__ x,
                                             const float* __restrict__ thresh,
                                             uint8_t* __restrict__ spk,
                                             float* __restrict__ ub_sum) {
    const float thre = thresh[0];
    const int e4   = blockIdx.x * 256 + threadIdx.x;
    const int base = e4 * 4;

    float    mem[4];
    int      cnt[4] = {0, 0, 0, 0};
    unsigned pb[4]  = {0, 0, 0, 0};
#pragma unroll
    for (int i = 0; i < 4; ++i) mem[i] = 0.5f * thre;

#pragma unroll
    for (int t = 0; t < T_; ++t) {
        const float4 xv = *reinterpret_cast<const float4*>(x + (size_t)t * N_ + base);
        const float xa[4] = {xv.x, xv.y, xv.z, xv.w};
#pragma unroll
        for (int i = 0; i < 4; ++i) {
            mem[i] += xa[i];
            if (mem[i] - thre >= 0.0f) {   // heaviside(mem - cur)
                mem[i] -= thre;            // mem - s*cur
                pb[i] |= (1u << t);
                cnt[i]++;
            }
        }
    }

    if (PACK) {
        reinterpret_cast<uchar4*>(spk)[e4] =
            make_uchar4((uint8_t)pb[0], (uint8_t)pb[1], (uint8_t)pb[2], (uint8_t)pb[3]);
    }

    // per-site new_thre, summed over this thread's 4 sites
    float local = 0.0f;
#pragma unroll
    for (int i = 0; i < 4; ++i) {
        const float compen_mem = mem[i] - 0.5f * thre;
        const float cv = fminf(compen_mem + (float)cnt[i] * thre, (float)T_ * thre);
        if (cv > 0.0f && cnt[i] > 0) local += cv / (float)cnt[i];
    }

    // wave64 shuffle reduce, then 4 wave partials via LDS, 1 atomic per block
#pragma unroll
    for (int off = 32; off > 0; off >>= 1) local += __shfl_down(local, off, 64);
    __shared__ float wpart[4];
    const int lane = threadIdx.x & 63;
    const int wid  = threadIdx.x >> 6;
    if (lane == 0) wpart[wid] = local;
    __syncthreads();
    if (threadIdx.x == 0) {
        const float tot = wpart[0] + wpart[1] + wpart[2] + wpart[3];
        const int c = blockIdx.x & (C_ - 1);  // block -> channel (block-uniform)
        atomicAdd(ub_sum + c, tot);
    }
}

// ---------------------------------------------------------------------------
// K2: ub[c] = sum/32768; update = 0.2 * mean_c((ub-thre) * (thre > ub));
//     scalar = thre + update
// ---------------------------------------------------------------------------
__global__ __launch_bounds__(128) void k_scalar(const float* __restrict__ ub_sum,
                                                const float* __restrict__ thresh,
                                                float* __restrict__ scal) {
    const float thre = thresh[0];
    const float ub   = ub_sum[threadIdx.x] * (1.0f / 32768.0f);
    float v = (thre > ub) ? (ub - thre) : 0.0f;
#pragma unroll
    for (int off = 32; off > 0; off >>= 1) v += __shfl_down(v, off, 64);
    __shared__ float part[2];
    if ((threadIdx.x & 63) == 0) part[threadIdx.x >> 6] = v;
    __syncthreads();
    if (threadIdx.x == 0) {
        const float update = LR_ * 2.0f * (part[0] + part[1]) * (1.0f / 128.0f);
        scal[0] = thre + update;
    }
}

// ---------------------------------------------------------------------------
// K3 (packed path): out[t, site] = spike_bit ? scalar : 0
// ---------------------------------------------------------------------------
__global__ __launch_bounds__(256) void k_out(const uint8_t* __restrict__ spk,
                                             const float* __restrict__ scal,
                                             float* __restrict__ out) {
    const int e4   = blockIdx.x * 256 + threadIdx.x;
    const int base = e4 * 4;
    const uchar4 p = reinterpret_cast<const uchar4*>(spk)[e4];
    const float  s = scal[0];
    const unsigned pb[4] = {p.x, p.y, p.z, p.w};
#pragma unroll
    for (int t = 0; t < T_; ++t) {
        float4 o;
        o.x = ((pb[0] >> t) & 1) ? s : 0.0f;
        o.y = ((pb[1] >> t) & 1) ? s : 0.0f;
        o.z = ((pb[2] >> t) & 1) ? s : 0.0f;
        o.w = ((pb[3] >> t) & 1) ? s : 0.0f;
        *reinterpret_cast<float4*>(out + (size_t)t * N_ + base) = o;
    }
}

// ---------------------------------------------------------------------------
// K3 fallback (ws too small for spike pack): recompute recurrence from x
// ---------------------------------------------------------------------------
__global__ __launch_bounds__(256) void k_out_recompute(const float* __restrict__ x,
                                                       const float* __restrict__ thresh,
                                                       const float* __restrict__ scal,
                                                       float* __restrict__ out) {
    const float thre = thresh[0];
    const float s    = scal[0];
    const int e4   = blockIdx.x * 256 + threadIdx.x;
    const int base = e4 * 4;
    float mem[4];
#pragma unroll
    for (int i = 0; i < 4; ++i) mem[i] = 0.5f * thre;
#pragma unroll
    for (int t = 0; t < T_; ++t) {
        const float4 xv = *reinterpret_cast<const float4*>(x + (size_t)t * N_ + base);
        const float xa[4] = {xv.x, xv.y, xv.z, xv.w};
        float4 o;
        float oo[4];
#pragma unroll
        for (int i = 0; i < 4; ++i) {
            mem[i] += xa[i];
            if (mem[i] - thre >= 0.0f) {
                mem[i] -= thre;
                oo[i] = s;
            } else {
                oo[i] = 0.0f;
            }
        }
        o.x = oo[0]; o.y = oo[1]; o.z = oo[2]; o.w = oo[3];
        *reinterpret_cast<float4*>(out + (size_t)t * N_ + base) = o;
    }
}

extern "C" void kernel_launch(void* const* d_in, const int* in_sizes, int n_in,
                              void* d_out, int out_size, void* d_ws, size_t ws_size,
                              hipStream_t stream) {
    const float* x      = (const float*)d_in[0];
    const float* thresh = (const float*)d_in[1];
    float*       out    = (float*)d_out;

    // ws layout: [0,512) ub_sum[128] | [512,516) scalar | [1024, 1024+N_) packed spikes
    float*   ub_sum = (float*)d_ws;
    float*   scal   = ub_sum + C_;
    uint8_t* spk    = (uint8_t*)d_ws + 1024;
    const bool pack = ws_size >= (size_t)(1024 + N_);

    hipMemsetAsync(d_ws, 0, 1024, stream);  // zero accumulators every call

    const int nblk = N_ / 4 / 256;  // 4096
    if (pack) {
        k_fwd<true><<<nblk, 256, 0, stream>>>(x, thresh, spk, ub_sum);
    } else {
        k_fwd<false><<<nblk, 256, 0, stream>>>(x, thresh, nullptr, ub_sum);
    }
    k_scalar<<<1, 128, 0, stream>>>(ub_sum, thresh, scal);
    if (pack) {
        k_out<<<nblk, 256, 0, stream>>>(spk, scal, out);
    } else {
        k_out_recompute<<<nblk, 256, 0, stream>>>(x, thresh, scal, out);
    }
}